// Round 10
// baseline (139.332 us; speedup 1.0000x reference)
//
#include <hip/hip_runtime.h>

// BahdanauAttention on MI355X — fp32 in/out. Scratch inside d_out.
//
// d_out float layout: ctx [0, 1048576), attn [1048576, 1310720).
// Phases 1-2 use ctx region as scratch:
//   qe  at [0,      524288): [1024][512]   e^{2*qproj}
//   kep at [524288,1048576): [4][512][256] e^{2*kproj}   (PURE, no ie2 now)
// Phase 3 (k2b) overwrites ctx region with the final context.
//
// Math: tanh(x) = 1 - 2/(e^{2x}+1); score = S - sum_u 2*s_u/(E+1), S=sum(s)
// cancels in softmax. acc = sum_u s_u*rcp(E+1) (pairwise-combined), softmax
// arg = -2*acc. E+1 = fma(qe, kep, 1) -> inline constant, no per-u additive
// load. Round 10: k1 v5 = 1024 blocks (4 waves/SIMD TLP, barrier-free,
// direct-global frags) per m102 small-shape diagnosis; k2a v5/k2b v4 =
// block-uniform operands via scalar cache, LDS removed from inner loops.

typedef unsigned int u32;
typedef unsigned short u16;
typedef __attribute__((ext_vector_type(8))) short s16x8;
typedef __attribute__((ext_vector_type(4))) float f32x4;
typedef __attribute__((ext_vector_type(4))) u32 u32x4;

union v4cast { u32x4 u; s16x8 s; };

// exact split of 8 fp32 -> bf16 hi (trunc) + bf16 lo (trunc of x - hi)
__device__ __forceinline__ void split8(const float* f, s16x8& h, s16x8& l) {
  v4cast hv, lv;
#pragma unroll
  for (int p = 0; p < 4; ++p) {
    u32 u0 = __float_as_uint(f[2 * p]);
    u32 u1 = __float_as_uint(f[2 * p + 1]);
    hv.u[p] = __builtin_amdgcn_perm(u1, u0, 0x07060302u);  // [u0.hi16,u1.hi16]
    float l0 = f[2 * p] - __uint_as_float(u0 & 0xffff0000u);
    float l1 = f[2 * p + 1] - __uint_as_float(u1 & 0xffff0000u);
    lv.u[p] = __builtin_amdgcn_perm(__float_as_uint(l1), __float_as_uint(l0),
                                    0x07060302u);
  }
  h = hv.s;
  l = lv.s;
}

// ---------- K1 v5: high-TLP LDS-free split-bf16 MFMA projections -----------
// grid (16, 32, 2) = 1024 blocks, block 256 = 4 waves (4 blocks/CU, 4 w/SIMD).
// Block tile 32m x 32n. wave: pos = w&1 -> m-half (16 rows); kh = w>>1 ->
// K half (512). Barrier-free K loop; one LDS reduce at the end.
__global__ __launch_bounds__(256, 4) void k1_mfma(
    const float* __restrict__ query, const float* __restrict__ value,
    const float* __restrict__ Wq, const float* __restrict__ Wk,
    float* __restrict__ outbuf) {
  const int z = blockIdx.z;
  const float* X = z ? value : query;  // [1024][1024]
  const float* W = z ? Wk : Wq;        // [1024][512]
  const int M0 = blockIdx.y * 32, N0 = blockIdx.x * 32;
  const int tid = threadIdx.x, lane = tid & 63, w = tid >> 6;
  const int pos = w & 1, kh = w >> 1;
  const int quad = lane >> 4, r16 = lane & 15;
  const int m = M0 + pos * 16 + r16;
  const float* aP = X + m * 1024 + kh * 512 + quad * 8;
  const float* bP = W + (kh * 512 + quad * 8) * 512 + N0 + r16;

  f32x4 acc0 = {0.f, 0.f, 0.f, 0.f}, acc1 = {0.f, 0.f, 0.f, 0.f};
#pragma unroll 2
  for (int i = 0; i < 16; ++i) {
    const int kb = i * 32;
    float4 xa = *(const float4*)(aP + kb);
    float4 xb = *(const float4*)(aP + kb + 4);
    float fb0[8], fb1[8];
    const float* bk = bP + kb * 512;
#pragma unroll
    for (int j = 0; j < 8; ++j) {
      fb0[j] = bk[j * 512];
      fb1[j] = bk[j * 512 + 16];
    }
    float fa[8] = {xa.x, xa.y, xa.z, xa.w, xb.x, xb.y, xb.z, xb.w};
    s16x8 aH, aL, bH0, bL0, bH1, bL1;
    split8(fa, aH, aL);
    split8(fb0, bH0, bL0);
    split8(fb1, bH1, bL1);
    acc0 = __builtin_amdgcn_mfma_f32_16x16x32_bf16(aH, bH0, acc0, 0, 0, 0);
    acc0 = __builtin_amdgcn_mfma_f32_16x16x32_bf16(aH, bL0, acc0, 0, 0, 0);
    acc0 = __builtin_amdgcn_mfma_f32_16x16x32_bf16(aL, bH0, acc0, 0, 0, 0);
    acc1 = __builtin_amdgcn_mfma_f32_16x16x32_bf16(aH, bH1, acc1, 0, 0, 0);
    acc1 = __builtin_amdgcn_mfma_f32_16x16x32_bf16(aH, bL1, acc1, 0, 0, 0);
    acc1 = __builtin_amdgcn_mfma_f32_16x16x32_bf16(aL, bH1, acc1, 0, 0, 0);
  }

  // cross-kh reduction (waves w and w+2 pair up), then epilogue on kh==0
  __shared__ __align__(16) float red[2][2][64][4];  // [pos][frag][lane][4]
  if (kh == 1) {
    *(f32x4*)red[pos][0][lane] = acc0;
    *(f32x4*)red[pos][1][lane] = acc1;
  }
  __syncthreads();
  if (kh == 0) {
    acc0 += *(const f32x4*)red[pos][0][lane];
    acc1 += *(const f32x4*)red[pos][1][lane];
    float* qe = outbuf;            // [1024][512]
    float* kep = outbuf + 524288;  // [4][512][256], pure e^{2k}
    const int mq = quad * 4;
#pragma unroll
    for (int f = 0; f < 2; ++f) {
      f32x4 ac = f ? acc1 : acc0;
      const int nn = N0 + f * 16 + r16;  // C/D: col = lane&15
#pragma unroll
      for (int r = 0; r < 4; ++r) {
        const int mm = M0 + pos * 16 + mq + r;  // C/D: row = quad*4+reg
        float e = __expf(2.f * ac[r]);
        if (z == 0) {
          qe[mm * 512 + nn] = e;
        } else {
          const int bb = mm >> 8, kl = mm & 255;
          kep[bb * 131072 + nn * 256 + kl] = e;
        }
      }
    }
  }
}

// ---------- K2a v5: scores + softmax, scalar-uniform qe/scale --------------
// grid 512 (= 4b x 128 q-pairs), block 256 (4 waves).
// thread: (k2 = tid&127 -> k2, k2+128) x (uh = tid>>7 -> u half) x 2 q.
// term pair (u0,u1): s0/A + s1/B = fma(s0,B,s1*A)*rcp(A*B), A/B = fma(qe,kv,1).
__global__ __launch_bounds__(256) void k2a_attn(
    const float* __restrict__ qe, const float* __restrict__ kep,
    const float* __restrict__ scale, float* __restrict__ attn) {
  const int b = blockIdx.x >> 7;
  const int q0 = (blockIdx.x & 127) * 2;
  const int tid = threadIdx.x;
  __shared__ float ps2[2][2][256];  // [uh][q][k] partial sums

  const int k2 = tid & 127, uh = tid >> 7;
  const float* kb = kep + b * 131072 + k2;
  const float* qr0 = qe + (b * 256 + q0) * 512;  // block-uniform -> s_load
  const float* qr1 = qr0 + 512;
  const int ub = uh * 256;
  float a00 = 0.f, a01 = 0.f, a10 = 0.f, a11 = 0.f;
#pragma unroll 4
  for (int up = 0; up < 128; ++up) {
    const int u0 = ub + 2 * up, u1 = u0 + 1;
    float kv00 = kb[u0 * 256];        // vector, coalesced, L2-resident
    float kv01 = kb[u0 * 256 + 128];
    float kv10 = kb[u1 * 256];
    float kv11 = kb[u1 * 256 + 128];
    float qa0 = qr0[u0], qa1 = qr0[u1];    // uniform (scalar cache)
    float qb0 = qr1[u0], qb1 = qr1[u1];
    float s0 = scale[u0], s1 = scale[u1];  // uniform (scalar cache)
    float A, B, r;
    A = fmaf(qa0, kv00, 1.f); B = fmaf(qa1, kv10, 1.f);
    r = __builtin_amdgcn_rcpf(A * B);
    a00 += fmaf(s0, B, s1 * A) * r;
    A = fmaf(qa0, kv01, 1.f); B = fmaf(qa1, kv11, 1.f);
    r = __builtin_amdgcn_rcpf(A * B);
    a01 += fmaf(s0, B, s1 * A) * r;
    A = fmaf(qb0, kv00, 1.f); B = fmaf(qb1, kv10, 1.f);
    r = __builtin_amdgcn_rcpf(A * B);
    a10 += fmaf(s0, B, s1 * A) * r;
    A = fmaf(qb0, kv01, 1.f); B = fmaf(qb1, kv11, 1.f);
    r = __builtin_amdgcn_rcpf(A * B);
    a11 += fmaf(s0, B, s1 * A) * r;
  }
  ps2[uh][0][k2] = a00;
  ps2[uh][0][k2 + 128] = a01;
  ps2[uh][1][k2] = a10;
  ps2[uh][1][k2 + 128] = a11;
  __syncthreads();

  const int w = tid >> 6, lane = tid & 63;
  if (w < 2) {  // wave w: softmax for q-row q0+w; arg = -2*acc
    float x0 = -2.f * (ps2[0][w][lane] + ps2[1][w][lane]);
    float x1 = -2.f * (ps2[0][w][lane + 64] + ps2[1][w][lane + 64]);
    float x2 = -2.f * (ps2[0][w][lane + 128] + ps2[1][w][lane + 128]);
    float x3 = -2.f * (ps2[0][w][lane + 192] + ps2[1][w][lane + 192]);
    float m = fmaxf(fmaxf(x0, x1), fmaxf(x2, x3));
    for (int off = 32; off; off >>= 1) m = fmaxf(m, __shfl_xor(m, off));
    float e0 = __expf(x0 - m), e1 = __expf(x1 - m);
    float e2 = __expf(x2 - m), e3 = __expf(x3 - m);
    float t = e0 + e1 + e2 + e3;
    for (int off = 32; off; off >>= 1) t += __shfl_xor(t, off);
    float inv = 1.0f / t;
    float* ar = attn + (b * 256 + q0 + w) * 256;
    ar[lane] = e0 * inv;
    ar[lane + 64] = e1 * inv;
    ar[lane + 128] = e2 * inv;
    ar[lane + 192] = e3 * inv;
  }
}

// ---------- K2b v4: ctx = attn @ value, scalar-uniform attn ----------------
// grid (2, 64, 4): d-half, 4 q-rows, batch. block 256, thread: 1 float2 x 4q.
__global__ __launch_bounds__(256) void k2b_ctx(
    const float* __restrict__ attn, const float* __restrict__ value,
    float* __restrict__ ctx) {
  const int dh = blockIdx.x, q0 = blockIdx.y * 4, b = blockIdx.z;
  const int tid = threadIdx.x;
  const float2* v2 = (const float2*)value + b * 131072 + dh * 256 + tid;
  const float* ar0 = attn + (b * 256 + q0) * 256;  // block-uniform rows
  const float* ar1 = ar0 + 256;
  const float* ar2 = ar0 + 512;
  const float* ar3 = ar0 + 768;
  float2 a0 = {0.f, 0.f}, a1 = a0, a2 = a0, a3 = a0;
#pragma unroll 2
  for (int k4 = 0; k4 < 256; k4 += 4) {
    float4 p0 = *(const float4*)(ar0 + k4);  // uniform -> s_load_dwordx4
    float4 p1 = *(const float4*)(ar1 + k4);
    float4 p2 = *(const float4*)(ar2 + k4);
    float4 p3 = *(const float4*)(ar3 + k4);
    float2 v0 = v2[(k4 + 0) * 512];          // vector, coalesced
    float2 vA = v2[(k4 + 1) * 512];
    float2 vB = v2[(k4 + 2) * 512];
    float2 vC = v2[(k4 + 3) * 512];
    a0.x = fmaf(p0.x, v0.x, a0.x); a0.y = fmaf(p0.x, v0.y, a0.y);
    a1.x = fmaf(p1.x, v0.x, a1.x); a1.y = fmaf(p1.x, v0.y, a1.y);
    a2.x = fmaf(p2.x, v0.x, a2.x); a2.y = fmaf(p2.x, v0.y, a2.y);
    a3.x = fmaf(p3.x, v0.x, a3.x); a3.y = fmaf(p3.x, v0.y, a3.y);
    a0.x = fmaf(p0.y, vA.x, a0.x); a0.y = fmaf(p0.y, vA.y, a0.y);
    a1.x = fmaf(p1.y, vA.x, a1.x); a1.y = fmaf(p1.y, vA.y, a1.y);
    a2.x = fmaf(p2.y, vA.x, a2.x); a2.y = fmaf(p2.y, vA.y, a2.y);
    a3.x = fmaf(p3.y, vA.x, a3.x); a3.y = fmaf(p3.y, vA.y, a3.y);
    a0.x = fmaf(p0.z, vB.x, a0.x); a0.y = fmaf(p0.z, vB.y, a0.y);
    a1.x = fmaf(p1.z, vB.x, a1.x); a1.y = fmaf(p1.z, vB.y, a1.y);
    a2.x = fmaf(p2.z, vB.x, a2.x); a2.y = fmaf(p2.z, vB.y, a2.y);
    a3.x = fmaf(p3.z, vB.x, a3.x); a3.y = fmaf(p3.z, vB.y, a3.y);
    a0.x = fmaf(p0.w, vC.x, a0.x); a0.y = fmaf(p0.w, vC.y, a0.y);
    a1.x = fmaf(p1.w, vC.x, a1.x); a1.y = fmaf(p1.w, vC.y, a1.y);
    a2.x = fmaf(p2.w, vC.x, a2.x); a2.y = fmaf(p2.w, vC.y, a2.y);
    a3.x = fmaf(p3.w, vC.x, a3.x); a3.y = fmaf(p3.w, vC.y, a3.y);
  }
  float2* c2 = (float2*)ctx;
  const int base = (b * 256 + q0) * 512 + dh * 256 + tid;
  c2[base] = a0;
  c2[base + 512] = a1;
  c2[base + 1024] = a2;
  c2[base + 1536] = a3;
}

extern "C" void kernel_launch(void* const* d_in, const int* in_sizes, int n_in,
                              void* d_out, int out_size, void* d_ws, size_t ws_size,
                              hipStream_t stream) {
  (void)d_ws; (void)ws_size;  // unused; scratch lives in d_out
  const float *query = nullptr, *value = nullptr, *Wq = nullptr, *Wk = nullptr,
              *scale = nullptr;
  for (int i = 0; i < n_in; ++i) {
    int s = in_sizes[i];
    if (s == 1048576) { if (!query) query = (const float*)d_in[i]; else if (!value) value = (const float*)d_in[i]; }
    else if (s == 524288) { if (!Wq) Wq = (const float*)d_in[i]; else if (!Wk) Wk = (const float*)d_in[i]; }
    else if (s == 512) { scale = (const float*)d_in[i]; }
  }
  float* ob = (float*)d_out;
  k1_mfma<<<dim3(16, 32, 2), 256, 0, stream>>>(query, value, Wq, Wk, ob);
  k2a_attn<<<dim3(512), 256, 0, stream>>>(ob, ob + 524288, scale, ob + 1048576);
  k2b_ctx<<<dim3(2, 64, 4), 256, 0, stream>>>(ob + 1048576, value, ob);
}

// Round 11
// 133.629 us; speedup vs baseline: 1.0427x; 1.0427x over previous
//
#include <hip/hip_runtime.h>

// BahdanauAttention on MI355X — fp32 in/out. Scratch inside d_out.
//
// d_out float layout: ctx [0, 1048576), attn [1048576, 1310720).
// Phases 1-2 use ctx region as scratch:
//   qe  at [0,      524288): [1024][512]   e^{2*qproj}
//   kep at [524288,1048576): [4][512][256] e^{2*kproj} * ie2[u], ie2=0.5/scale
// Phase 3 (k2b) overwrites ctx region with the final context.
//
// Math: tanh(x) = 1 - 2/(e^{2x}+1); score = S - sum_u 2*s_u/(E+1), S=sum(s)
// cancels in softmax. term = 1/(ie2*(E+1)) = 2s/(E+1); pairwise combine
// 1/A + 1/B = (A+B)*rcp(A*B) halves rcp count. softmax arg = -acc.
//
// Round 11: single-variable test vs R9 (131.6us): k1 v4 -> v5 (1024 blocks,
// 4 blocks/CU TLP, barrier-free direct-global frags; ie2 restored in kep
// epilogue). k2a v4 and k2b v2 are verbatim R9 (R10's k2a v5 "uniform"
// loads were wave- but not compiler-provably-uniform -> 6 extra VMEM/iter;
// k2b v4 s_load chains serialize on lgkmcnt -> both reverted).

typedef unsigned int u32;
typedef unsigned short u16;
typedef __attribute__((ext_vector_type(8))) short s16x8;
typedef __attribute__((ext_vector_type(4))) float f32x4;
typedef __attribute__((ext_vector_type(4))) u32 u32x4;

union v4cast { u32x4 u; s16x8 s; };

// exact split of 8 fp32 -> bf16 hi (trunc) + bf16 lo (trunc of x - hi)
__device__ __forceinline__ void split8(const float* f, s16x8& h, s16x8& l) {
  v4cast hv, lv;
#pragma unroll
  for (int p = 0; p < 4; ++p) {
    u32 u0 = __float_as_uint(f[2 * p]);
    u32 u1 = __float_as_uint(f[2 * p + 1]);
    hv.u[p] = __builtin_amdgcn_perm(u1, u0, 0x07060302u);  // [u0.hi16,u1.hi16]
    float l0 = f[2 * p] - __uint_as_float(u0 & 0xffff0000u);
    float l1 = f[2 * p + 1] - __uint_as_float(u1 & 0xffff0000u);
    lv.u[p] = __builtin_amdgcn_perm(__float_as_uint(l1), __float_as_uint(l0),
                                    0x07060302u);
  }
  h = hv.s;
  l = lv.s;
}

// ---------- K1 v5: high-TLP LDS-free split-bf16 MFMA projections -----------
// grid (16, 32, 2) = 1024 blocks, block 256 = 4 waves (4 blocks/CU, 4 w/SIMD).
// Block tile 32m x 32n. wave: pos = w&1 -> m-half (16 rows); kh = w>>1 ->
// K half (512). Barrier-free K loop; one LDS reduce at the end.
__global__ __launch_bounds__(256, 4) void k1_mfma(
    const float* __restrict__ query, const float* __restrict__ value,
    const float* __restrict__ Wq, const float* __restrict__ Wk,
    const float* __restrict__ scale, float* __restrict__ outbuf) {
  const int z = blockIdx.z;
  const float* X = z ? value : query;  // [1024][1024]
  const float* W = z ? Wk : Wq;        // [1024][512]
  const int M0 = blockIdx.y * 32, N0 = blockIdx.x * 32;
  const int tid = threadIdx.x, lane = tid & 63, w = tid >> 6;
  const int pos = w & 1, kh = w >> 1;
  const int quad = lane >> 4, r16 = lane & 15;
  const int m = M0 + pos * 16 + r16;
  const float* aP = X + m * 1024 + kh * 512 + quad * 8;
  const float* bP = W + (kh * 512 + quad * 8) * 512 + N0 + r16;

  f32x4 acc0 = {0.f, 0.f, 0.f, 0.f}, acc1 = {0.f, 0.f, 0.f, 0.f};
#pragma unroll 2
  for (int i = 0; i < 16; ++i) {
    const int kb = i * 32;
    float4 xa = *(const float4*)(aP + kb);
    float4 xb = *(const float4*)(aP + kb + 4);
    float fb0[8], fb1[8];
    const float* bk = bP + kb * 512;
#pragma unroll
    for (int j = 0; j < 8; ++j) {
      fb0[j] = bk[j * 512];
      fb1[j] = bk[j * 512 + 16];
    }
    float fa[8] = {xa.x, xa.y, xa.z, xa.w, xb.x, xb.y, xb.z, xb.w};
    s16x8 aH, aL, bH0, bL0, bH1, bL1;
    split8(fa, aH, aL);
    split8(fb0, bH0, bL0);
    split8(fb1, bH1, bL1);
    acc0 = __builtin_amdgcn_mfma_f32_16x16x32_bf16(aH, bH0, acc0, 0, 0, 0);
    acc0 = __builtin_amdgcn_mfma_f32_16x16x32_bf16(aH, bL0, acc0, 0, 0, 0);
    acc0 = __builtin_amdgcn_mfma_f32_16x16x32_bf16(aL, bH0, acc0, 0, 0, 0);
    acc1 = __builtin_amdgcn_mfma_f32_16x16x32_bf16(aH, bH1, acc1, 0, 0, 0);
    acc1 = __builtin_amdgcn_mfma_f32_16x16x32_bf16(aH, bL1, acc1, 0, 0, 0);
    acc1 = __builtin_amdgcn_mfma_f32_16x16x32_bf16(aL, bH1, acc1, 0, 0, 0);
  }

  // cross-kh reduction (waves w and w+2 pair up), then epilogue on kh==0
  __shared__ __align__(16) float red[2][2][64][4];  // [pos][frag][lane][4]
  if (kh == 1) {
    *(f32x4*)red[pos][0][lane] = acc0;
    *(f32x4*)red[pos][1][lane] = acc1;
  }
  __syncthreads();
  if (kh == 0) {
    acc0 += *(const f32x4*)red[pos][0][lane];
    acc1 += *(const f32x4*)red[pos][1][lane];
    float* qe = outbuf;            // [1024][512]
    float* kep = outbuf + 524288;  // [4][512][256], e^{2k} * ie2
    const int mq = quad * 4;
#pragma unroll
    for (int f = 0; f < 2; ++f) {
      f32x4 ac = f ? acc1 : acc0;
      const int nn = N0 + f * 16 + r16;  // C/D: col = lane&15
      float i2 = 0.f;
      if (z) i2 = 0.5f / scale[nn];
#pragma unroll
      for (int r = 0; r < 4; ++r) {
        const int mm = M0 + pos * 16 + mq + r;  // C/D: row = quad*4+reg
        float e = __expf(2.f * ac[r]);
        if (z == 0) {
          qe[mm * 512 + nn] = e;
        } else {
          const int bb = mm >> 8, kl = mm & 255;
          kep[bb * 131072 + nn * 256 + kl] = e * i2;
        }
      }
    }
  }
}

// ---------- K2a v4 (R9 verbatim): scores + softmax, rcp-pair combine -------
// grid 512 (= 4b x 128 q-pairs), block 256 (4 waves).
// thread: (k2 = tid&127 -> k2, k2+128) x (uh = tid>>7 -> u half) x 2 q.
__global__ __launch_bounds__(256) void k2a_attn(
    const float* __restrict__ qe, const float* __restrict__ kep,
    const float* __restrict__ scale, float* __restrict__ attn) {
  const int b = blockIdx.x >> 7;
  const int q0 = (blockIdx.x & 127) * 2;
  const int tid = threadIdx.x;
  __shared__ __align__(16) float4 qh[512];   // [u]{qe_q0, qe_q1, ie2, 0}
  __shared__ float ps2[2][2][256];           // [uh][q][k] partial sums

  const float* qr = qe + (b * 256 + q0) * 512;
#pragma unroll
  for (int i = 0; i < 2; ++i) {
    int u = tid + i * 256;
    float4 v;
    v.x = qr[u];
    v.y = qr[512 + u];
    v.z = 0.5f / scale[u];
    v.w = 0.f;
    qh[u] = v;
  }
  __syncthreads();

  const int k2 = tid & 127, uh = tid >> 7;
  const float* kb = kep + b * 131072 + k2;
  const int ub = uh * 256;
  float a00 = 0.f, a01 = 0.f, a10 = 0.f, a11 = 0.f;
#pragma unroll 4
  for (int up = 0; up < 128; ++up) {
    const int u0 = ub + 2 * up, u1 = u0 + 1;
    float kv00 = kb[u0 * 256];        // (u0, k2)     coalesced
    float kv01 = kb[u0 * 256 + 128];  // (u0, k2+128)
    float kv10 = kb[u1 * 256];
    float kv11 = kb[u1 * 256 + 128];
    float4 qa = qh[u0], qb = qh[u1];  // wave-uniform b128 broadcasts
    float A, B;
    A = fmaf(qa.x, kv00, qa.z); B = fmaf(qb.x, kv10, qb.z);
    a00 += (A + B) * __builtin_amdgcn_rcpf(A * B);
    A = fmaf(qa.x, kv01, qa.z); B = fmaf(qb.x, kv11, qb.z);
    a01 += (A + B) * __builtin_amdgcn_rcpf(A * B);
    A = fmaf(qa.y, kv00, qa.z); B = fmaf(qb.y, kv10, qb.z);
    a10 += (A + B) * __builtin_amdgcn_rcpf(A * B);
    A = fmaf(qa.y, kv01, qa.z); B = fmaf(qb.y, kv11, qb.z);
    a11 += (A + B) * __builtin_amdgcn_rcpf(A * B);
  }
  ps2[uh][0][k2] = a00;
  ps2[uh][0][k2 + 128] = a01;
  ps2[uh][1][k2] = a10;
  ps2[uh][1][k2 + 128] = a11;
  __syncthreads();

  const int w = tid >> 6, lane = tid & 63;
  if (w < 2) {  // wave w: softmax for q-row q0+w
    float x0 = -(ps2[0][w][lane] + ps2[1][w][lane]);
    float x1 = -(ps2[0][w][lane + 64] + ps2[1][w][lane + 64]);
    float x2 = -(ps2[0][w][lane + 128] + ps2[1][w][lane + 128]);
    float x3 = -(ps2[0][w][lane + 192] + ps2[1][w][lane + 192]);
    float m = fmaxf(fmaxf(x0, x1), fmaxf(x2, x3));
    for (int off = 32; off; off >>= 1) m = fmaxf(m, __shfl_xor(m, off));
    float e0 = __expf(x0 - m), e1 = __expf(x1 - m);
    float e2 = __expf(x2 - m), e3 = __expf(x3 - m);
    float t = e0 + e1 + e2 + e3;
    for (int off = 32; off; off >>= 1) t += __shfl_xor(t, off);
    float inv = 1.0f / t;
    float* ar = attn + (b * 256 + q0 + w) * 256;
    ar[lane] = e0 * inv;
    ar[lane + 64] = e1 * inv;
    ar[lane + 128] = e2 * inv;
    ar[lane + 192] = e3 * inv;
  }
}

// ---------- K2b v2 (R9 verbatim): ctx = attn @ value -----------------------
// grid (2, 64, 4): d-half, 4 q-rows, batch. block 256, thread: 1 float2 x 4q.
__global__ __launch_bounds__(256) void k2b_ctx(
    const float* __restrict__ attn, const float* __restrict__ value,
    float* __restrict__ ctx) {
  const int dh = blockIdx.x, q0 = blockIdx.y * 4, b = blockIdx.z;
  const int tid = threadIdx.x;
  __shared__ __align__(16) float pl[256 * 4];  // [k][r]
#pragma unroll
  for (int r = 0; r < 4; ++r)
    pl[tid * 4 + r] = attn[(b * 256 + q0 + r) * 256 + tid];
  __syncthreads();
  const float2* v2 = (const float2*)value + b * 131072 + dh * 256 + tid;
  const float4* pl4 = (const float4*)pl;
  float2 a0 = {0.f, 0.f}, a1 = a0, a2 = a0, a3 = a0;
#pragma unroll 8
  for (int kk = 0; kk < 256; ++kk) {
    float2 v = v2[kk * 512];
    float4 p = pl4[kk];  // LDS broadcast b128
    a0.x = fmaf(p.x, v.x, a0.x); a0.y = fmaf(p.x, v.y, a0.y);
    a1.x = fmaf(p.y, v.x, a1.x); a1.y = fmaf(p.y, v.y, a1.y);
    a2.x = fmaf(p.z, v.x, a2.x); a2.y = fmaf(p.z, v.y, a2.y);
    a3.x = fmaf(p.w, v.x, a3.x); a3.y = fmaf(p.w, v.y, a3.y);
  }
  float2* c2 = (float2*)ctx;
  const int base = (b * 256 + q0) * 512 + dh * 256 + tid;
  c2[base] = a0;
  c2[base + 512] = a1;
  c2[base + 1024] = a2;
  c2[base + 1536] = a3;
}

extern "C" void kernel_launch(void* const* d_in, const int* in_sizes, int n_in,
                              void* d_out, int out_size, void* d_ws, size_t ws_size,
                              hipStream_t stream) {
  (void)d_ws; (void)ws_size;  // unused; scratch lives in d_out
  const float *query = nullptr, *value = nullptr, *Wq = nullptr, *Wk = nullptr,
              *scale = nullptr;
  for (int i = 0; i < n_in; ++i) {
    int s = in_sizes[i];
    if (s == 1048576) { if (!query) query = (const float*)d_in[i]; else if (!value) value = (const float*)d_in[i]; }
    else if (s == 524288) { if (!Wq) Wq = (const float*)d_in[i]; else if (!Wk) Wk = (const float*)d_in[i]; }
    else if (s == 512) { scale = (const float*)d_in[i]; }
  }
  float* ob = (float*)d_out;
  k1_mfma<<<dim3(16, 32, 2), 256, 0, stream>>>(query, value, Wq, Wk, scale, ob);
  k2a_attn<<<dim3(512), 256, 0, stream>>>(ob, ob + 524288, scale, ob + 1048576);
  k2b_ctx<<<dim3(2, 64, 4), 256, 0, stream>>>(ob + 1048576, value, ob);
}